// Round 1
// baseline (310.189 us; speedup 1.0000x reference)
//
#include <hip/hip_runtime.h>
#include <cstdint>

// BasisFunction1D: out[o,b] = sum_i (1-d)*P[idx,o,i] + d*P[idx+1,o,i]
//
// R7 strategy (bank-deterministic gather):
//   Q3[((os*128+i)*128+g)*32+om] = pack_f16(P, dP), o = os*32+om.
//   Per (i,b) the 32-o slice is a CONTIGUOUS 128B run -> gathered by 8 lanes
//   (quad = lane&7, data-INDEPENDENT) -> exactly 8 rows/bank, no Poisson
//   imbalance from random idx. T packs (idx*128)|f16(d)<<16 so the ds addr
//   is one v_and_or.
//   Grid decomposition: os(4) x btile(8 x 1024 b) x ichunk(8 x 16 i) = 256
//   blocks (1/CU), XCD-chunked so the 8 b-tile blocks sharing a (os,ic)
//   Q3 slice (256KB) land on one XCD's L2.
//   i-split partials: part[ic][b][o] f32 (33.5MB, L3-resident), reduced by
//   reduce_k (coalesced read, LDS-transposed write).
//   Staging: global_load_lds width=16, double-buffered 2x16KB slabs.

#define NG 128
#define NI 128
#define NO 128
#define NB 8192

using half2v = __attribute__((ext_vector_type(2))) _Float16;

__device__ inline uint32_t pack_f16x2(float lo, float hi) {
    _Float16 hl = (_Float16)lo, hh = (_Float16)hi;
    return (uint32_t)__builtin_bit_cast(unsigned short, hl) |
           ((uint32_t)__builtin_bit_cast(unsigned short, hh) << 16);
}

__device__ inline void load_lds16(const uint32_t* g, uint32_t* l) {
    __builtin_amdgcn_global_load_lds(
        (const __attribute__((address_space(1))) uint32_t*)g,
        (__attribute__((address_space(3))) uint32_t*)l, 16, 0, 0);
}

// ---- K1: P[g,o,i] -> Q3[((os*NI+i)*NG+g)*32 + om] = pack(P, dP) ----------
// block = (g, os); stores are 64B-per-thread full-line coalesced (the old
// layout scattered 16B at 2KB stride -> partial-line write amplification).
__global__ __launch_bounds__(256) void build_q(const float* __restrict__ P,
                                               uint32_t* __restrict__ Q3) {
    __shared__ float lp[32][129];
    __shared__ float ln[32][129];
    const int g  = blockIdx.x >> 2;
    const int os = blockIdx.x & 3;
    const int o0 = os * 32;
    const int t  = threadIdx.x;
    #pragma unroll
    for (int p = 0; p < 16; ++p) {
        int e = p * 256 + t;
        int ol = e >> 7, i = e & 127;
        lp[ol][i] = P[(size_t)(g * NO + o0 + ol) * NI + i];
        ln[ol][i] = P[(size_t)((g + 1) * NO + o0 + ol) * NI + i];
    }
    __syncthreads();
    const int i   = t >> 1;
    const int om0 = (t & 1) * 16;
    uint32_t r[16];
    #pragma unroll
    for (int j = 0; j < 16; ++j) {
        int om = om0 + j;
        float pl = lp[om][i];
        float dd = ln[om][i] - pl;
        r[j] = pack_f16x2(pl, dd);
    }
    uint32_t* dst = Q3 + ((size_t)(os * NI + i) * NG + g) * 32 + om0;
    *(uint4*)(dst)      = make_uint4(r[0],  r[1],  r[2],  r[3]);
    *(uint4*)(dst + 4)  = make_uint4(r[4],  r[5],  r[6],  r[7]);
    *(uint4*)(dst + 8)  = make_uint4(r[8],  r[9],  r[10], r[11]);
    *(uint4*)(dst + 12) = make_uint4(r[12], r[13], r[14], r[15]);
}

// ---- K2: bucketize x -> T[i][b] = (idx*128) | (f16(d) << 16) -------------
// low16 is a ready BYTE offset into the [g][32om] slab (128B per g-row).
__global__ __launch_bounds__(256) void build_t(const float* __restrict__ x,
                                               const float* __restrict__ borders,
                                               const float* __restrict__ icl,
                                               uint32_t* __restrict__ T) {
    const int e0 = (blockIdx.x * 256 + threadIdx.x) * 4;
    const float4 xv = *(const float4*)(x + e0);
    uint32_t r[4];
    const float xs[4] = {xv.x, xv.y, xv.z, xv.w};
    #pragma unroll
    for (int k = 0; k < 4; ++k) {
        float v = xs[k];
        float ea = __expf(-fabsf(v));
        float cdf = v > 0.f ? 1.f - 0.5f * ea : 0.5f * ea;
        int idx = (int)(cdf * 128.f);
        idx = idx > 127 ? 127 : idx;
        float d = (v - borders[idx]) * icl[idx];
        _Float16 hd = (_Float16)d;
        r[k] = ((uint32_t)idx << 7) |
               ((uint32_t)__builtin_bit_cast(unsigned short, hd) << 16);
    }
    *(uint4*)(T + e0) = make_uint4(r[0], r[1], r[2], r[3]);
}

// ---- K3: main. 1024 thr; (32 o x 1024 b x 16 i) per block ----------------
// lane l: q = l&7 (o-quad within the 32-o slice), b-octet (l>>3); round r
// handles b = bbase + r. Gather: 8 lanes x 16B = 128B contiguous per (i,b)
// -> bank quad = q, deterministic, exactly 8 rows/bank.
__global__ __launch_bounds__(1024) void main_k(const uint32_t* __restrict__ Q3,
                                               const uint32_t* __restrict__ T,
                                               float* __restrict__ part) {
    __shared__ uint32_t slab[2][4096];          // 2 x 16KB double buffer
    const int t   = threadIdx.x;
    const int bx  = blockIdx.x;
    const int wid = ((bx & 7) << 5) | (bx >> 3);   // XCD-chunked swizzle
    const int bt  = wid & 7;
    const int os  = (wid >> 3) & 3;
    const int ic  = wid >> 5;
    const int w = t >> 6, l = t & 63;
    const int q = l & 7;
    const int bbase = (bt << 10) + (w << 6) + ((l >> 3) << 3);
    const uint32_t qoff = (uint32_t)q << 4;
    const uint32_t* Qs = Q3 + ((size_t)os * NI + ic * 16) * (NG * 32) + t * 4;
    const uint32_t* Ts = T + (size_t)(ic * 16) * NB + bbase;

    float4 acc[8];
    #pragma unroll
    for (int r = 0; r < 8; ++r) acc[r] = make_float4(0.f, 0.f, 0.f, 0.f);

    // prologue: stage i=0 slab + this lane's 8 T words
    load_lds16(Qs, &slab[0][t * 4]);
    uint4 ta = *(const uint4*)(Ts);
    uint4 tb = *(const uint4*)(Ts + 4);
    __syncthreads();                            // vmcnt(0) drain -> slab[0] ready

    #pragma unroll
    for (int ii = 0; ii < 16; ++ii) {
        const int cur = ii & 1;
        if (ii < 15) {                          // issue next-i stage early
            load_lds16(Qs + (ii + 1) * (NG * 32), &slab[cur ^ 1][t * 4]);
        }
        uint4 na, nb;
        if (ii < 15) {
            na = *(const uint4*)(Ts + (size_t)(ii + 1) * NB);
            nb = *(const uint4*)(Ts + (size_t)(ii + 1) * NB + 4);
        }
        const char* sp = (const char*)&slab[cur][0];
        const uint32_t tc[8] = {ta.x, ta.y, ta.z, ta.w, tb.x, tb.y, tb.z, tb.w};
        #pragma unroll
        for (int r = 0; r < 8; ++r) {
            uint32_t tw  = tc[r];
            uint32_t off = (tw & 0xFFFFu) | qoff;           // idx*128 + q*16
            uint32_t w2b = (tw & 0xFFFF0000u) | 0x3C00u;    // {1.0h, d}
            uint4 qv = *(const uint4*)(sp + off);
            half2v w2 = __builtin_bit_cast(half2v, w2b);
            acc[r].x = __builtin_amdgcn_fdot2(__builtin_bit_cast(half2v, qv.x), w2, acc[r].x, false);
            acc[r].y = __builtin_amdgcn_fdot2(__builtin_bit_cast(half2v, qv.y), w2, acc[r].y, false);
            acc[r].z = __builtin_amdgcn_fdot2(__builtin_bit_cast(half2v, qv.z), w2, acc[r].z, false);
            acc[r].w = __builtin_amdgcn_fdot2(__builtin_bit_cast(half2v, qv.w), w2, acc[r].w, false);
        }
        if (ii < 15) {
            ta = na; tb = nb;
            __syncthreads();                    // drains stage(ii+1)
        }
    }

    // partial store: part[ic][b][o] -- 8 lanes x 16B = 128B contiguous per b
    float* pp = part + ((size_t)ic * NB + bbase) * NO + os * 32 + (q << 2);
    #pragma unroll
    for (int r = 0; r < 8; ++r)
        *(float4*)(pp + (size_t)r * NO) = acc[r];
}

// ---- K4: reduce 8 i-chunk partials, transpose [b][o] -> out[o][b] --------
__global__ __launch_bounds__(256) void reduce_k(const float* __restrict__ part,
                                                float* __restrict__ out) {
    __shared__ float ts[NO][17];                // pad 17 -> conflict-lite
    const int t  = threadIdx.x;
    const int b0 = blockIdx.x * 16;
    #pragma unroll
    for (int p = 0; p < 2; ++p) {
        const int c  = p * 256 + t;             // 0..511 = 16 b x 32 o-quads
        const int bl = c >> 5;
        const int o4 = (c & 31) * 4;
        const float* src = part + ((size_t)(b0 + bl)) * NO + o4;
        float4 s = *(const float4*)(src);
        #pragma unroll
        for (int icc = 1; icc < 8; ++icc) {
            float4 v = *(const float4*)(src + (size_t)icc * NB * NO);
            s.x += v.x; s.y += v.y; s.z += v.z; s.w += v.w;
        }
        ts[o4 + 0][bl] = s.x;
        ts[o4 + 1][bl] = s.y;
        ts[o4 + 2][bl] = s.z;
        ts[o4 + 3][bl] = s.w;
    }
    __syncthreads();
    const int bl  = t & 15;
    const int orr = t >> 4;
    #pragma unroll
    for (int k = 0; k < 8; ++k) {
        const int o = orr + k * 16;
        __builtin_nontemporal_store(ts[o][bl], out + (size_t)o * NB + b0 + bl);
    }
}

extern "C" void kernel_launch(void* const* d_in, const int* in_sizes, int n_in,
                              void* d_out, int out_size, void* d_ws, size_t ws_size,
                              hipStream_t stream) {
    const float* x       = (const float*)d_in[0];
    const float* P       = (const float*)d_in[1];
    const float* borders = (const float*)d_in[2];
    const float* icl     = (const float*)d_in[3];
    float* out = (float*)d_out;

    uint32_t* Q3  = (uint32_t*)d_ws;                        // 8.4 MB
    uint32_t* T   = Q3 + (size_t)4 * NI * NG * 32;          // 4.2 MB
    float*    prt = (float*)(T + (size_t)NI * NB);          // 33.5 MB

    hipLaunchKernelGGL(build_q, dim3(NG * 4), dim3(256), 0, stream, P, Q3);
    hipLaunchKernelGGL(build_t, dim3(NI * NB / 1024), dim3(256), 0, stream,
                       x, borders, icl, T);
    hipLaunchKernelGGL(main_k, dim3(256), dim3(1024), 0, stream, Q3, T, prt);
    hipLaunchKernelGGL(reduce_k, dim3(NB / 16), dim3(256), 0, stream, prt, out);
}

// Round 2
// 100.693 us; speedup vs baseline: 3.0805x; 3.0805x over previous
//
#include <hip/hip_runtime.h>
#include <cstdint>

// BasisFunction1D: out[o,b] = sum_i (1-d)*P[idx,o,i] + d*P[idx+1,o,i]
//
// R8 = R6 (93.7us verified) + main_k split into 2 barrier domains per CU.
//   R7 post-mortem: i-split partials caused 733MB HBM RMW traffic; 1 blk/CU
//   made every per-phase vmcnt(0) barrier drain a CU-wide stall. Reverted.
//   R8 main_k: 512 blocks x 512 thr (b-tile 512), slab 32KB/block -> two
//   independent blocks per CU overlap: one computes while the other drains.
//   Everything else identical to R6.

#define NG 128
#define NI 128
#define NO 128
#define NB 8192
#define WO 4
#define PH 8
#define NPH (NI / PH)

using half2v = __attribute__((ext_vector_type(2))) _Float16;

__device__ inline uint32_t pack_f16x2(float lo, float hi) {
    _Float16 hl = (_Float16)lo, hh = (_Float16)hi;
    return (uint32_t)__builtin_bit_cast(unsigned short, hl) |
           ((uint32_t)__builtin_bit_cast(unsigned short, hh) << 16);
}

// ---- K1: P[g,o,i] -> Q2[((s*NI+i)*NG+g)*4+ow] = pack(P, dP), o=s*4+ow ----
__global__ __launch_bounds__(256) void build_q(const float* __restrict__ P,
                                               uint32_t* __restrict__ Q2) {
    __shared__ float lp[32][129];
    __shared__ float ln[32][129];
    const int g  = blockIdx.x >> 2;
    const int o0 = (blockIdx.x & 3) * 32;
    const int t  = threadIdx.x;
    #pragma unroll
    for (int p = 0; p < 16; ++p) {
        int e = p * 256 + t;
        int ol = e >> 7, i = e & 127;
        lp[ol][i] = P[(size_t)(g * NO + o0 + ol) * NI + i];
        ln[ol][i] = P[(size_t)((g + 1) * NO + o0 + ol) * NI + i];
    }
    __syncthreads();
    #pragma unroll
    for (int p = 0; p < 4; ++p) {
        int e = p * 256 + t;          // 8 s_loc x 128 i
        int sl = e >> 7, i = e & 127;
        uint32_t r[4];
        #pragma unroll
        for (int ow = 0; ow < 4; ++ow) {
            float pl = lp[sl * 4 + ow][i];
            float dd = ln[sl * 4 + ow][i] - pl;
            r[ow] = pack_f16x2(pl, dd);
        }
        int s = (o0 >> 2) + sl;
        *(uint4*)(Q2 + ((size_t)(s * NI + i) * NG + g) * 4) =
            make_uint4(r[0], r[1], r[2], r[3]);
    }
}

// ---- K2: bucketize x -> T[i][b] = (idx*16) | (f16(d) << 16) ----
__global__ __launch_bounds__(256) void build_t(const float* __restrict__ x,
                                               const float* __restrict__ borders,
                                               const float* __restrict__ icl,
                                               uint32_t* __restrict__ T) {
    const int e0 = (blockIdx.x * 256 + threadIdx.x) * 4;
    const float4 xv = *(const float4*)(x + e0);
    uint32_t r[4];
    const float xs[4] = {xv.x, xv.y, xv.z, xv.w};
    #pragma unroll
    for (int k = 0; k < 4; ++k) {
        float v = xs[k];
        float ea = __expf(-fabsf(v));
        float cdf = v > 0.f ? 1.f - 0.5f * ea : 0.5f * ea;
        int idx = (int)(cdf * 128.f);
        idx = idx > 127 ? 127 : idx;
        float d = (v - borders[idx]) * icl[idx];
        _Float16 hd = (_Float16)d;
        r[k] = ((uint32_t)idx << 4) |
               ((uint32_t)__builtin_bit_cast(unsigned short, hd) << 16);
    }
    *(uint4*)(T + e0) = make_uint4(r[0], r[1], r[2], r[3]);
}

// ---- K3: main. 512 thr; 512 b x 4 o per block; 2 blocks/CU overlap ----
__global__ __launch_bounds__(512, 8) void main_k(const uint32_t* __restrict__ Q2,
                                                 const uint32_t* __restrict__ T,
                                                 float* __restrict__ out) {
    __shared__ uint32_t slab[2][PH][NG * WO];   // 32 KB
    const int t    = threadIdx.x;
    const int bx   = blockIdx.x;
    const int s    = bx & 31;                   // o-slice (4 o); same-s blocks
    const int bblk = (bx >> 5) << 9;            //   share one XCD (bx%8==s%8)
    const int bme  = bblk + t;                  // lane's batch
    const uint32_t* Qs = Q2 + (size_t)s * NI * NG * WO;

    float a0 = 0.f, a1 = 0.f, a2 = 0.f, a3 = 0.f;

    // prologue: stage phase 0 (each thread stages 2x16B of the 16KB slab)
    uint32_t treg[PH];
    {
        uint4 qa = *(const uint4*)(Qs + (size_t)t * 4);
        uint4 qb = *(const uint4*)(Qs + 2048 + (size_t)t * 4);
        #pragma unroll
        for (int il = 0; il < PH; ++il)
            treg[il] = T[(size_t)il * NB + bme];
        ((uint4*)&slab[0][0][0])[t]       = qa;
        ((uint4*)&slab[0][0][0])[t + 512] = qb;
    }
    __syncthreads();

    #pragma unroll
    for (int p = 0; p < NPH; ++p) {
        const int cur = p & 1;
        uint32_t tnxt[PH];
        uint4 qna, qnb;
        if (p < NPH - 1) {
            qna = *(const uint4*)(Qs + (size_t)(p + 1) * (PH * NG * WO) +
                                  (size_t)t * 4);
            qnb = *(const uint4*)(Qs + (size_t)(p + 1) * (PH * NG * WO) +
                                  2048 + (size_t)t * 4);
            #pragma unroll
            for (int il = 0; il < PH; ++il)
                tnxt[il] = T[(size_t)((p + 1) * PH + il) * NB + bme];
        }
        #pragma unroll
        for (int il = 0; il < PH; ++il) {
            uint32_t tw  = treg[il];
            uint32_t off = tw & 0xFFFFu;                    // idx*16 bytes
            uint32_t w2b = (tw & 0xFFFF0000u) | 0x3C00u;    // {1.0h, d}
            uint4 q = *(const uint4*)((const char*)&slab[cur][il][0] + off);
            half2v w2 = __builtin_bit_cast(half2v, w2b);
            a0 = __builtin_amdgcn_fdot2(__builtin_bit_cast(half2v, q.x), w2, a0, false);
            a1 = __builtin_amdgcn_fdot2(__builtin_bit_cast(half2v, q.y), w2, a1, false);
            a2 = __builtin_amdgcn_fdot2(__builtin_bit_cast(half2v, q.z), w2, a2, false);
            a3 = __builtin_amdgcn_fdot2(__builtin_bit_cast(half2v, q.w), w2, a3, false);
        }
        if (p < NPH - 1) {
            ((uint4*)&slab[cur ^ 1][0][0])[t]       = qna;
            ((uint4*)&slab[cur ^ 1][0][0])[t + 512] = qnb;
            #pragma unroll
            for (int il = 0; il < PH; ++il)
                treg[il] = tnxt[il];
            __syncthreads();
        }
    }

    // epilogue: o = s*4 + {0..3}; 512-lane contiguous runs per o
    size_t ob = (size_t)(s * 4) * NB + bme;
    __builtin_nontemporal_store(a0, out + ob);
    __builtin_nontemporal_store(a1, out + ob + NB);
    __builtin_nontemporal_store(a2, out + ob + 2 * (size_t)NB);
    __builtin_nontemporal_store(a3, out + ob + 3 * (size_t)NB);
}

extern "C" void kernel_launch(void* const* d_in, const int* in_sizes, int n_in,
                              void* d_out, int out_size, void* d_ws, size_t ws_size,
                              hipStream_t stream) {
    const float* x       = (const float*)d_in[0];
    const float* P       = (const float*)d_in[1];
    const float* borders = (const float*)d_in[2];
    const float* icl     = (const float*)d_in[3];
    float* out = (float*)d_out;

    uint32_t* Q2 = (uint32_t*)d_ws;                 // 8 MB
    uint32_t* T  = Q2 + (size_t)NO * NI * NG;       // 4 MB

    hipLaunchKernelGGL(build_q, dim3(NG * 4), dim3(256), 0, stream, P, Q2);
    hipLaunchKernelGGL(build_t, dim3(NI * NB / 1024), dim3(256), 0, stream,
                       x, borders, icl, T);
    hipLaunchKernelGGL(main_k, dim3((NB / 512) * 32), dim3(512), 0, stream,
                       Q2, T, out);
}

// Round 4
// 92.582 us; speedup vs baseline: 3.3504x; 1.0876x over previous
//
#include <hip/hip_runtime.h>
#include <cstdint>

// BasisFunction1D: out[o,b] = sum_i (1-d)*P[idx,o,i] + d*P[idx+1,o,i]
//
// R10 = R9 with the nontemporal-store compile fix (native ext_vector float4).
//   main_k: i-split by 2 (each block does 64 i, 8 phases), grid 512 x 1024thr
//     -> 2 blocks/CU = 32 waves/CU (R6/R8 had 16). Same per-CU LDS work.
//     Halves write disjoint full-line partial buffers; reduce_k sums them.
//   build_q: block = 4g x 16o x 128i; each thread stores 64B contiguous
//     (R6 scattered 16B @ 2KB stride -> partial-line RMW amplification).

#define NG 128
#define NI 128
#define NO 128
#define NB 8192
#define WO 4
#define PH 8

using half2v = __attribute__((ext_vector_type(2))) _Float16;
using float4v = __attribute__((ext_vector_type(4))) float;

__device__ inline uint32_t pack_f16x2(float lo, float hi) {
    _Float16 hl = (_Float16)lo, hh = (_Float16)hi;
    return (uint32_t)__builtin_bit_cast(unsigned short, hl) |
           ((uint32_t)__builtin_bit_cast(unsigned short, hh) << 16);
}

// ---- K1: P[g,o,i] -> Q2[((s*NI+i)*NG+g)*4+ow] = pack(P, dP), o=s*4+ow ----
// block: g0=4g, o0=16o (4 s). Each thread computes 4g x 4ow for its (s,i)
// and stores 4 x uint4 = 64B contiguous (g fastest-dim adjacency).
__global__ __launch_bounds__(256) void build_q(const float* __restrict__ P,
                                               uint32_t* __restrict__ Q2) {
    __shared__ float L[5][16][128];             // 40 KB
    const int gb = blockIdx.x >> 3;
    const int ob = blockIdx.x & 7;
    const int g0 = gb * 4;
    const int o0 = ob * 16;
    const int s0 = ob * 4;
    const int t  = threadIdx.x;
    #pragma unroll
    for (int pass = 0; pass < 40; ++pass) {     // 80 rows x 128 i
        int row = pass * 2 + (t >> 7);
        int i   = t & 127;
        int gg  = row >> 4, ol = row & 15;
        L[gg][ol][i] = P[(size_t)(g0 + gg) * (NO * NI) + (o0 + ol) * NI + i];
    }
    __syncthreads();
    #pragma unroll
    for (int pp = 0; pp < 2; ++pp) {
        int item = pp * 256 + t;                // 4 sl x 128 i
        int i  = item & 127;
        int sl = item >> 7;
        uint32_t* dst = Q2 + ((size_t)((s0 + sl) * NI + i) * NG + g0) * 4;
        #pragma unroll
        for (int gg = 0; gg < 4; ++gg) {
            uint32_t r[4];
            #pragma unroll
            for (int ow = 0; ow < 4; ++ow) {
                float pl = L[gg][sl * 4 + ow][i];
                float dd = L[gg + 1][sl * 4 + ow][i] - pl;
                r[ow] = pack_f16x2(pl, dd);
            }
            *(uint4*)(dst + gg * 4) = make_uint4(r[0], r[1], r[2], r[3]);
        }
    }
}

// ---- K2: bucketize x -> T[i][b] = (idx*16) | (f16(d) << 16) ----
__global__ __launch_bounds__(256) void build_t(const float* __restrict__ x,
                                               const float* __restrict__ borders,
                                               const float* __restrict__ icl,
                                               uint32_t* __restrict__ T) {
    const int e0 = (blockIdx.x * 256 + threadIdx.x) * 4;
    const float4 xv = *(const float4*)(x + e0);
    uint32_t r[4];
    const float xs[4] = {xv.x, xv.y, xv.z, xv.w};
    #pragma unroll
    for (int k = 0; k < 4; ++k) {
        float v = xs[k];
        float ea = __expf(-fabsf(v));
        float cdf = v > 0.f ? 1.f - 0.5f * ea : 0.5f * ea;
        int idx = (int)(cdf * 128.f);
        idx = idx > 127 ? 127 : idx;
        float d = (v - borders[idx]) * icl[idx];
        _Float16 hd = (_Float16)d;
        r[k] = ((uint32_t)idx << 4) |
               ((uint32_t)__builtin_bit_cast(unsigned short, hd) << 16);
    }
    *(uint4*)(T + e0) = make_uint4(r[0], r[1], r[2], r[3]);
}

// ---- K3: main. 1024 thr; 1024 b x 4 o x 64 i per block; 2 blocks/CU ----
__global__ __launch_bounds__(1024, 8) void main_k(const uint32_t* __restrict__ Q2,
                                                  const uint32_t* __restrict__ T,
                                                  float* __restrict__ part) {
    __shared__ uint32_t slab[2][PH][NG * WO];   // 32 KB
    const int t    = threadIdx.x;
    const int bx   = blockIdx.x;
    const int s    = bx & 31;                   // o-slice (4 o); same-s blocks
    const int ih   = (bx >> 5) & 1;             //   share one XCD (bx%8==s%8)
    const int bblk = (bx >> 6) << 10;           // b-tile of 1024
    const int bme  = bblk + t;                  // lane's batch
    const uint32_t* Qs = Q2 + ((size_t)s * NI + ih * 64) * (NG * WO);
    const uint32_t* Ts = T + (size_t)(ih * 64) * NB;

    float a0 = 0.f, a1 = 0.f, a2 = 0.f, a3 = 0.f;

    // prologue: stage phase 0 (16 KB; each thread 16B) + 8 T words
    uint32_t treg[PH];
    {
        uint4 q0 = *(const uint4*)(Qs + (size_t)t * 4);
        #pragma unroll
        for (int il = 0; il < PH; ++il)
            treg[il] = Ts[(size_t)il * NB + bme];
        ((uint4*)&slab[0][0][0])[t] = q0;
    }
    __syncthreads();

    #pragma unroll
    for (int p = 0; p < 8; ++p) {
        const int cur = p & 1;
        uint32_t tnxt[PH];
        uint4 qnxt;
        if (p < 7) {
            qnxt = *(const uint4*)(Qs + (size_t)(p + 1) * (PH * NG * WO) +
                                   (size_t)t * 4);
            #pragma unroll
            for (int il = 0; il < PH; ++il)
                tnxt[il] = Ts[(size_t)((p + 1) * PH + il) * NB + bme];
        }
        #pragma unroll
        for (int il = 0; il < PH; ++il) {
            uint32_t tw  = treg[il];
            uint32_t off = tw & 0xFFFFu;                    // idx*16 bytes
            uint32_t w2b = (tw & 0xFFFF0000u) | 0x3C00u;    // {1.0h, d}
            uint4 q = *(const uint4*)((const char*)&slab[cur][il][0] + off);
            half2v w2 = __builtin_bit_cast(half2v, w2b);
            a0 = __builtin_amdgcn_fdot2(__builtin_bit_cast(half2v, q.x), w2, a0, false);
            a1 = __builtin_amdgcn_fdot2(__builtin_bit_cast(half2v, q.y), w2, a1, false);
            a2 = __builtin_amdgcn_fdot2(__builtin_bit_cast(half2v, q.z), w2, a2, false);
            a3 = __builtin_amdgcn_fdot2(__builtin_bit_cast(half2v, q.w), w2, a3, false);
        }
        if (p < 7) {
            ((uint4*)&slab[cur ^ 1][0][0])[t] = qnxt;
            #pragma unroll
            for (int il = 0; il < PH; ++il)
                treg[il] = tnxt[il];
            __syncthreads();
        }
    }

    // partial store: part[ih][o][b]; 1024-lane contiguous 4KB runs per o
    float* po = part + (size_t)ih * (NO * NB) + (size_t)(s * 4) * NB + bme;
    __builtin_nontemporal_store(a0, po);
    __builtin_nontemporal_store(a1, po + NB);
    __builtin_nontemporal_store(a2, po + 2 * (size_t)NB);
    __builtin_nontemporal_store(a3, po + 3 * (size_t)NB);
}

// ---- K4: out = part0 + part1 (1M floats) ----
__global__ __launch_bounds__(256) void reduce_k(const float* __restrict__ part,
                                                float* __restrict__ out) {
    const int e0 = (blockIdx.x * 256 + threadIdx.x) * 4;
    const float4v v0 = *(const float4v*)(part + e0);
    const float4v v1 = *(const float4v*)(part + (size_t)NO * NB + e0);
    const float4v r = v0 + v1;
    __builtin_nontemporal_store(r, (float4v*)(out + e0));
}

extern "C" void kernel_launch(void* const* d_in, const int* in_sizes, int n_in,
                              void* d_out, int out_size, void* d_ws, size_t ws_size,
                              hipStream_t stream) {
    const float* x       = (const float*)d_in[0];
    const float* P       = (const float*)d_in[1];
    const float* borders = (const float*)d_in[2];
    const float* icl     = (const float*)d_in[3];
    float* out = (float*)d_out;

    uint32_t* Q2 = (uint32_t*)d_ws;                 // 8 MB
    uint32_t* T  = Q2 + (size_t)NO * NI * NG;       // 4 MB
    float*    prt = (float*)(T + (size_t)NI * NB);  // 8 MB (two halves)

    hipLaunchKernelGGL(build_q, dim3(256), dim3(256), 0, stream, P, Q2);
    hipLaunchKernelGGL(build_t, dim3(NI * NB / 1024), dim3(256), 0, stream,
                       x, borders, icl, T);
    hipLaunchKernelGGL(main_k, dim3(512), dim3(1024), 0, stream, Q2, T, prt);
    hipLaunchKernelGGL(reduce_k, dim3(NO * NB / 1024), dim3(256), 0, stream,
                       prt, out);
}